// Round 5
// baseline (7093.389 us; speedup 1.0000x reference)
//
#include <hip/hip_runtime.h>
#include <hip/hip_bf16.h>

// AttentiveFuturecaster R5.
//  - af_pack: repack weights into MFMA-fragment order (one wave-load = 1 KB
//    contiguous) for eWhh/eWih/dWhh/f1W; bf16.
//  - af_encoder: 256 blocks x 512 thr, BTE=8. h carried as bf16 hi+lo pairs
//    FUSED into one 16-row MFMA A-tile (rows 0..7 hi, 8..15 lo; gate value =
//    D[m]+D[m+8] via shfl_xor 32). Wih register-resident. Emits hs + A/C.
//  - af_decoder: 512 blocks x 256 thr, BTD=4, 1 block/CU. Each wave holds its
//    batch row's full hs history in 256 VGPRs (u64 hreg[128]) -> ctx phase has
//    ZERO memory traffic. ctx hi/lo fused rows 0..3/4..7, combine via
//    shfl_xor 16. Weights streamed from L2 via packed fragments.
// ws: hs bf16 [B,T,H] | As fp32 [B,T] | Cs fp32 [B,T] | packed weights (1 MB).

#define B_    2048
#define T_    128
#define F_    64
#define H_    256
#define OUT_  32
#define BTE_  8
#define BTD_  4
#define NBE_  (B_ / BTE_)   // 256
#define NBD_  (B_ / BTD_)   // 512
#define HSTR_ 264
#define XSTR_ 72

// packed blob section offsets (bf16 elements)
#define PK_EHH_ 0
#define PK_EIH_ 196608
#define PK_DHH_ 245760
#define PK_F1_  442368
#define PK_TOT_ 507904

typedef __attribute__((ext_vector_type(8))) short bf16x8;
typedef __attribute__((ext_vector_type(4))) float f32x4;
typedef unsigned long long u64;

__device__ __forceinline__ f32x4 mfma16(bf16x8 a, bf16x8 b, f32x4 c) {
  return __builtin_amdgcn_mfma_f32_16x16x32_bf16(a, b, c, 0, 0, 0);
}
__device__ __forceinline__ float sigm_(float x) { return 1.0f / (1.0f + __expf(-x)); }
__device__ __forceinline__ float tanh_(float x) {
  x = fminf(15.0f, fmaxf(-15.0f, x));
  float e = __expf(2.0f * x);
  return (e - 1.0f) / (e + 1.0f);
}
__device__ __forceinline__ unsigned short f2bf_(float f) {
  unsigned u = __float_as_uint(f);
  return (unsigned short)((u + 0x7FFFu + ((u >> 16) & 1u)) >> 16);
}
__device__ __forceinline__ float bf2f_(unsigned short s) {
  return __uint_as_float(((unsigned)s) << 16);
}
__device__ __forceinline__ float bfl_(const __hip_bfloat16* p) {
  return __bfloat162float(*p);
}

// ---------------- weight repack: fragment-ordered, coalesced ----------------
__global__ __launch_bounds__(256) void af_pack(
    const float* __restrict__ eWih, const float* __restrict__ eWhh,
    const float* __restrict__ dWhh, const float* __restrict__ f1W,
    __hip_bfloat16* __restrict__ wb) {
  int i = blockIdx.x * blockDim.x + threadIdx.x;
  if (i >= PK_TOT_) return;
  float v;
  if (i < PK_EIH_) {                      // eWhh: chunk=(gm*16+c)*8+kk
    int q = i, j = q & 7, lane = (q >> 3) & 63, chunk = q >> 9;
    int kk = chunk & 7, c = (chunk >> 3) & 15, gm = chunk >> 7;
    int l16 = lane & 15, quad = lane >> 4;
    v = eWhh[(size_t)(gm * H_ + c * 16 + l16) * H_ + kk * 32 + quad * 8 + j];
  } else if (i < PK_DHH_) {               // eWih: chunk=(gm*16+c)*2+kk
    int q = i - PK_EIH_, j = q & 7, lane = (q >> 3) & 63, chunk = q >> 9;
    int kk = chunk & 1, c = (chunk >> 1) & 15, gm = chunk >> 5;
    int l16 = lane & 15, quad = lane >> 4;
    v = eWih[(size_t)(gm * H_ + c * 16 + l16) * F_ + kk * 32 + quad * 8 + j];
  } else if (i < PK_F1_) {                // dWhh
    int q = i - PK_DHH_, j = q & 7, lane = (q >> 3) & 63, chunk = q >> 9;
    int kk = chunk & 7, c = (chunk >> 3) & 15, gm = chunk >> 7;
    int l16 = lane & 15, quad = lane >> 4;
    v = dWhh[(size_t)(gm * H_ + c * 16 + l16) * H_ + kk * 32 + quad * 8 + j];
  } else {                                // f1W: chunk=c*8+kk
    int q = i - PK_F1_, j = q & 7, lane = (q >> 3) & 63, chunk = q >> 9;
    int kk = chunk & 7, c = chunk >> 3;
    int l16 = lane & 15, quad = lane >> 4;
    v = f1W[(size_t)(c * 16 + l16) * H_ + kk * 32 + quad * 8 + j];
  }
  wb[i] = __float2bfloat16(v);
}

// ============================ ENCODER ============================
__global__ __launch_bounds__(512, 2) void af_encoder(
    const float* __restrict__ x,
    const float* __restrict__ h0,
    const float* __restrict__ ebih,
    const float* __restrict__ ebhh,
    const float* __restrict__ aWq,
    const float* __restrict__ abq,
    const __hip_bfloat16* __restrict__ wp,
    __hip_bfloat16* __restrict__ hs,
    float* __restrict__ As,
    float* __restrict__ Cs)
{
  __shared__ __hip_bfloat16 sh[16 * HSTR_];      // rows 0..7 h-hi, 8..15 h-lo
  __shared__ __hip_bfloat16 sx[2][16 * XSTR_];   // rows 0..7 x-hi, 8..15 x-lo
  __shared__ float s_ebr[H_], s_ebz[H_], s_ebin[H_], s_ebhn[H_];
  __shared__ float s_wq[H_], s_bq[H_];

  const int tid  = threadIdx.x;
  const int b0   = blockIdx.x * BTE_;
  const int lane = tid & 63;
  const int wid  = tid >> 6;    // 0..7
  const int quad = lane >> 4;
  const int l16  = lane & 15;
  const int row  = wid;         // batch row for staging/output phases
  const int cg   = lane;

  if (tid < H_) {
    s_ebr[tid]  = ebih[tid]          + ebhh[tid];
    s_ebz[tid]  = ebih[H_ + tid]     + ebhh[H_ + tid];
    s_ebin[tid] = ebih[2 * H_ + tid];
    s_ebhn[tid] = ebhh[2 * H_ + tid];
    s_wq[tid]   = aWq[tid] * 0.0625f;
    s_bq[tid]   = abq[tid] * 0.0625f;
  }
  {
    const int c4 = cg * 4;
    float4 v4 = *(const float4*)(h0 + (size_t)(b0 + row) * H_ + c4);
    float vv[4] = {v4.x, v4.y, v4.z, v4.w};
#pragma unroll
    for (int j = 0; j < 4; ++j) {
      unsigned short hb = f2bf_(vv[j]);
      sh[row * HSTR_ + c4 + j]       = __float2bfloat16(vv[j]);
      sh[(row + 8) * HSTR_ + c4 + j] = __float2bfloat16(vv[j] - bf2f_(hb));
    }
    float xv = x[((size_t)(b0 + row) * T_) * F_ + cg];
    unsigned short xh = f2bf_(xv);
    sx[0][row * XSTR_ + cg]       = __float2bfloat16(xv);
    sx[0][(row + 8) * XSTR_ + cg] = __float2bfloat16(xv - bf2f_(xh));
  }
  __syncthreads();

  // register-resident Wih fragments + per-column biases
  bf16x8 qx[2][3][2];
  float bR[2], bZ[2], bI[2], bH[2];
#pragma unroll
  for (int s2 = 0; s2 < 2; ++s2) {
    const int c = 2 * wid + s2, g = c * 16 + l16;
    bR[s2] = s_ebr[g]; bZ[s2] = s_ebz[g]; bI[s2] = s_ebin[g]; bH[s2] = s_ebhn[g];
#pragma unroll
    for (int gm = 0; gm < 3; ++gm)
#pragma unroll
      for (int kk = 0; kk < 2; ++kk)
        qx[s2][gm][kk] = *(const bf16x8*)(wp + PK_EIH_ +
            (size_t)((gm * 16 + c) * 2 + kk) * 512 + lane * 8);
  }

  for (int t = 0; t < T_; ++t) {
    const int cur = t & 1, nxt = cur ^ 1;

    // phase 1: preload fused hi/lo A-fragments; prefetch x(t+1)
    bf16x8 ah[8], axf[2];
#pragma unroll
    for (int kk = 0; kk < 8; ++kk)
      ah[kk] = *(const bf16x8*)&sh[l16 * HSTR_ + kk * 32 + quad * 8];
#pragma unroll
    for (int kk = 0; kk < 2; ++kk)
      axf[kk] = *(const bf16x8*)&sx[cur][l16 * XSTR_ + kk * 32 + quad * 8];
    if (t + 1 < T_) {
      float xv = x[((size_t)(b0 + row) * T_ + (t + 1)) * F_ + cg];
      unsigned short xh = f2bf_(xv);
      sx[nxt][row * XSTR_ + cg]       = __float2bfloat16(xv);
      sx[nxt][(row + 8) * XSTR_ + cg] = __float2bfloat16(xv - bf2f_(xh));
    }
    __syncthreads();

    // phase 2: MFMA (hi/lo fused rows) + gate math + in-place h update
#pragma unroll
    for (int s2 = 0; s2 < 2; ++s2) {
      const int c = 2 * wid + s2, g = c * 16 + l16;
      const __hip_bfloat16* wb_ = wp + PK_EHH_ + (size_t)(c * 8) * 512 + lane * 8;
      f32x4 ar = {0.f, 0.f, 0.f, 0.f}, az = ar, ani = ar, anh = ar;
#pragma unroll
      for (int kk = 0; kk < 8; ++kk) {
        bf16x8 br = *(const bf16x8*)(wb_ + kk * 512);
        bf16x8 bz = *(const bf16x8*)(wb_ + 65536 + kk * 512);
        bf16x8 bn = *(const bf16x8*)(wb_ + 131072 + kk * 512);
        ar  = mfma16(ah[kk], br, ar);
        az  = mfma16(ah[kk], bz, az);
        anh = mfma16(ah[kk], bn, anh);
      }
#pragma unroll
      for (int kk = 0; kk < 2; ++kk) {
        ar  = mfma16(axf[kk], qx[s2][0][kk], ar);
        az  = mfma16(axf[kk], qx[s2][1][kk], az);
        ani = mfma16(axf[kk], qx[s2][2][kk], ani);
      }
#pragma unroll
      for (int i = 0; i < 4; ++i) {
        float vr = ar[i]  + __shfl_xor(ar[i],  32);
        float vz = az[i]  + __shfl_xor(az[i],  32);
        float vi = ani[i] + __shfl_xor(ani[i], 32);
        float vh = anh[i] + __shfl_xor(anh[i], 32);
        if (quad < 2) {
          const int m = quad * 4 + i;          // batch row 0..7
          float r = sigm_(vr + bR[s2]);
          float z = sigm_(vz + bZ[s2]);
          float n = tanh_(vi + bI[s2] + r * (vh + bH[s2]));
          float hold = bfl_(&sh[m * HSTR_ + g]) + bfl_(&sh[(m + 8) * HSTR_ + g]);
          float hn = (1.0f - z) * n + z * hold;
          unsigned short hb = f2bf_(hn);
          sh[m * HSTR_ + g]       = __float2bfloat16(hn);
          sh[(m + 8) * HSTR_ + g] = __float2bfloat16(hn - bf2f_(hb));
        }
      }
    }
    __syncthreads();

    // phase 3: hs store (nontemporal) + A/C rank-1 tables (scale folded)
    {
      const int c4 = cg * 4;
      u64 hv = *(const u64*)&sh[row * HSTR_ + c4];
      __builtin_nontemporal_store(
          hv, (u64*)(hs + ((size_t)(b0 + row) * T_ + t) * H_ + c4));
      float pa = 0.f, pc = 0.f;
#pragma unroll
      for (int j = 0; j < 4; ++j) {
        float hvf = bfl_(&sh[row * HSTR_ + c4 + j]) +
                    bfl_(&sh[(row + 8) * HSTR_ + c4 + j]);
        pa = fmaf(hvf, s_wq[c4 + j], pa);
        pc = fmaf(hvf, s_bq[c4 + j], pc);
      }
#pragma unroll
      for (int off = 32; off >= 1; off >>= 1) {
        pa += __shfl_xor(pa, off, 64);
        pc += __shfl_xor(pc, off, 64);
      }
      if (cg == 0) {
        As[(size_t)(b0 + row) * T_ + t] = pa;
        Cs[(size_t)(b0 + row) * T_ + t] = pc;
      }
    }
  }
}

// ============================ DECODER ============================
__global__ __launch_bounds__(256, 1) void af_decoder(
    const float* __restrict__ x,
    const float* __restrict__ dWih,
    const float* __restrict__ dbih,
    const float* __restrict__ dbhh,
    const float* __restrict__ f1b,
    const float* __restrict__ f2W,
    const float* __restrict__ f2b,
    const __hip_bfloat16* __restrict__ wp,
    const __hip_bfloat16* __restrict__ hs,
    const float* __restrict__ As,
    const float* __restrict__ Cs,
    float* __restrict__ dout)
{
  __shared__ __hip_bfloat16 ctx_t[16 * HSTR_];  // rows 0..3 hi, 4..7 lo, 8..15 junk
  __shared__ __hip_bfloat16 hd_t[16 * HSTR_];   // same packing
  __shared__ float ctxf[4 * 260];
  __shared__ float f1f[4 * 260];
  __shared__ float sA[4 * T_], sC[4 * T_], s_w[4 * 132];
  __shared__ float s_dbr[H_], s_dbz[H_], s_dbin[H_], s_dbhn[H_];
  __shared__ float s_dwih[3 * H_];
  __shared__ float s_f1b[H_], s_f2w[H_];
  __shared__ float s_f2b, s_prev[BTD_];

  const int tid  = threadIdx.x;
  const int b0   = blockIdx.x * BTD_;
  const int lane = tid & 63;
  const int wid  = tid >> 6;    // 0..3: wave = batch row
  const int quad = lane >> 4;
  const int l16  = lane & 15;

  s_dbr[tid]  = dbih[tid]          + dbhh[tid];
  s_dbz[tid]  = dbih[H_ + tid]     + dbhh[H_ + tid];
  s_dbin[tid] = dbih[2 * H_ + tid];
  s_dbhn[tid] = dbhh[2 * H_ + tid];
  s_f1b[tid]  = f1b[tid];
  s_f2w[tid]  = f2W[tid];
  for (int i = tid; i < 3 * H_; i += 256) s_dwih[i] = dWih[i];
  {
    sA[tid]       = As[(size_t)(b0 + (tid >> 7)) * T_ + (tid & 127)];
    sA[tid + 256] = As[(size_t)(b0 + 2 + (tid >> 7)) * T_ + (tid & 127)];
    sC[tid]       = Cs[(size_t)(b0 + (tid >> 7)) * T_ + (tid & 127)];
    sC[tid + 256] = Cs[(size_t)(b0 + 2 + (tid >> 7)) * T_ + (tid & 127)];
  }
  if (tid < BTD_) s_prev[tid] = x[((size_t)(b0 + tid) * T_ + (T_ - 1)) * F_];
  if (tid == 0) s_f2b = f2b[0];

  // whole hs history for this wave's batch row -> 256 VGPRs
  u64 hreg[T_];
  {
    const __hip_bfloat16* hp = hs + (size_t)(b0 + wid) * T_ * H_ + lane * 4;
#pragma unroll
    for (int t = 0; t < T_; ++t)
      hreg[t] = __builtin_nontemporal_load((const u64*)(hp + (size_t)t * H_));
  }
  __syncthreads();

#pragma unroll 1
  for (int s = 0; s < OUT_; ++s) {
    // P1: softmax over T (intra-wave; lane covers t and t+64)
    {
      const float pv = s_prev[wid];
      float sc0 = fmaf(pv, sA[wid * T_ + lane],      sC[wid * T_ + lane]);
      float sc1 = fmaf(pv, sA[wid * T_ + lane + 64], sC[wid * T_ + lane + 64]);
      float mx = fmaxf(sc0, sc1);
#pragma unroll
      for (int off = 32; off >= 1; off >>= 1) mx = fmaxf(mx, __shfl_xor(mx, off, 64));
      float e0 = __expf(sc0 - mx), e1 = __expf(sc1 - mx);
      float ss = e0 + e1;
#pragma unroll
      for (int off = 32; off >= 1; off >>= 1) ss += __shfl_xor(ss, off, 64);
      const float inv = 1.0f / ss;
      s_w[wid * 132 + lane]      = e0 * inv;
      s_w[wid * 132 + lane + 64] = e1 * inv;
    }
    // P2: ctx from registers (zero memory traffic)
    {
      float a0 = 0.f, a1 = 0.f, a2 = 0.f, a3 = 0.f;
      const float* wrow = &s_w[wid * 132];
#pragma unroll
      for (int t = 0; t < T_; ++t) {
        const float wt = wrow[t];
        const unsigned lo = (unsigned)hreg[t], hi2 = (unsigned)(hreg[t] >> 32);
        a0 = fmaf(wt, __uint_as_float(lo << 16),          a0);
        a1 = fmaf(wt, __uint_as_float(lo & 0xFFFF0000u),  a1);
        a2 = fmaf(wt, __uint_as_float(hi2 << 16),         a2);
        a3 = fmaf(wt, __uint_as_float(hi2 & 0xFFFF0000u), a3);
      }
      const int c4 = lane * 4;
      float vv[4] = {a0, a1, a2, a3};
#pragma unroll
      for (int j = 0; j < 4; ++j) {
        ctxf[wid * 260 + c4 + j] = vv[j];
        unsigned short hb = f2bf_(vv[j]);
        ctx_t[wid * HSTR_ + c4 + j]       = __float2bfloat16(vv[j]);
        ctx_t[(wid + 4) * HSTR_ + c4 + j] = __float2bfloat16(vv[j] - bf2f_(hb));
      }
    }
    __syncthreads();

    // P3: decoder GRU (MFMA, hi/lo fused rows 0..3/4..7)
    {
      bf16x8 ah[8];
#pragma unroll
      for (int kk = 0; kk < 8; ++kk)
        ah[kk] = *(const bf16x8*)&ctx_t[l16 * HSTR_ + kk * 32 + quad * 8];
#pragma unroll
      for (int s3 = 0; s3 < 4; ++s3) {
        const int c = wid * 4 + s3, g = c * 16 + l16;
        const __hip_bfloat16* wb_ = wp + PK_DHH_ + (size_t)(c * 8) * 512 + lane * 8;
        f32x4 ar = {0.f, 0.f, 0.f, 0.f}, az = ar, anh = ar;
#pragma unroll
        for (int kk = 0; kk < 8; ++kk) {
          bf16x8 br = *(const bf16x8*)(wb_ + kk * 512);
          bf16x8 bz = *(const bf16x8*)(wb_ + 65536 + kk * 512);
          bf16x8 bn = *(const bf16x8*)(wb_ + 131072 + kk * 512);
          ar  = mfma16(ah[kk], br, ar);
          az  = mfma16(ah[kk], bz, az);
          anh = mfma16(ah[kk], bn, anh);
        }
#pragma unroll
        for (int i = 0; i < 4; ++i) {
          float vr = ar[i]  + __shfl_xor(ar[i],  16);
          float vz = az[i]  + __shfl_xor(az[i],  16);
          float vh = anh[i] + __shfl_xor(anh[i], 16);
          if (quad == 0) {
            const int m = i;
            const float pv = s_prev[m];
            float r = sigm_(vr + fmaf(pv, s_dwih[g],          s_dbr[g]));
            float z = sigm_(vz + fmaf(pv, s_dwih[H_ + g],     s_dbz[g]));
            float n = tanh_(fmaf(pv, s_dwih[2 * H_ + g], s_dbin[g]) +
                            r * (vh + s_dbhn[g]));
            float hd = (1.0f - z) * n + z * ctxf[m * 260 + g];
            unsigned short hb = f2bf_(hd);
            hd_t[m * HSTR_ + g]       = __float2bfloat16(hd);
            hd_t[(m + 4) * HSTR_ + g] = __float2bfloat16(hd - bf2f_(hb));
          }
        }
      }
    }
    __syncthreads();

    // P4: fc1 + relu (MFMA, hi/lo fused)
    {
      bf16x8 ad[8];
#pragma unroll
      for (int kk = 0; kk < 8; ++kk)
        ad[kk] = *(const bf16x8*)&hd_t[l16 * HSTR_ + kk * 32 + quad * 8];
#pragma unroll
      for (int s3 = 0; s3 < 4; ++s3) {
        const int c = wid * 4 + s3, jc = c * 16 + l16;
        const __hip_bfloat16* wb_ = wp + PK_F1_ + (size_t)(c * 8) * 512 + lane * 8;
        f32x4 a1 = {0.f, 0.f, 0.f, 0.f};
#pragma unroll
        for (int kk = 0; kk < 8; ++kk)
          a1 = mfma16(ad[kk], *(const bf16x8*)(wb_ + kk * 512), a1);
#pragma unroll
        for (int i = 0; i < 4; ++i) {
          float v = a1[i] + __shfl_xor(a1[i], 16);
          if (quad == 0)
            f1f[i * 260 + jc] = fmaxf(v + s_f1b[jc], 0.0f);
        }
      }
    }
    __syncthreads();

    // P5: fc2 dot -> out, update prev (intra-wave next P1; cross-wave uses
    // later barriers: P3(s+1) reads s_prev after P2(s+1) barrier)
    {
      const int c4 = lane * 4;
      float p = 0.f;
#pragma unroll
      for (int j = 0; j < 4; ++j)
        p = fmaf(f1f[wid * 260 + c4 + j], s_f2w[c4 + j], p);
#pragma unroll
      for (int off = 32; off >= 1; off >>= 1) p += __shfl_xor(p, off, 64);
      if (lane == 0) {
        float o = p + s_f2b;
        s_prev[wid] = o;
        dout[(size_t)(b0 + wid) * OUT_ + s] = o;
      }
    }
    __syncthreads();
  }
}

extern "C" void kernel_launch(void* const* d_in, const int* in_sizes, int n_in,
                              void* d_out, int out_size, void* d_ws, size_t ws_size,
                              hipStream_t stream) {
  (void)in_sizes; (void)n_in; (void)out_size; (void)ws_size;
  const float* x    = (const float*)d_in[0];
  const float* h0   = (const float*)d_in[1];
  const float* eWih = (const float*)d_in[2];
  const float* eWhh = (const float*)d_in[3];
  const float* ebih = (const float*)d_in[4];
  const float* ebhh = (const float*)d_in[5];
  const float* dWih = (const float*)d_in[6];
  const float* dWhh = (const float*)d_in[7];
  const float* dbih = (const float*)d_in[8];
  const float* dbhh = (const float*)d_in[9];
  const float* aWq  = (const float*)d_in[10];
  const float* abq  = (const float*)d_in[11];
  const float* f1W  = (const float*)d_in[12];
  const float* f1b  = (const float*)d_in[13];
  const float* f2W  = (const float*)d_in[14];
  const float* f2b  = (const float*)d_in[15];

  char* wsb = (char*)d_ws;
  __hip_bfloat16* hs = (__hip_bfloat16*)wsb;                       // 134,217,728 B
  float* As = (float*)(wsb + (size_t)B_ * T_ * H_ * 2);            // 1 MB
  float* Cs = As + (size_t)B_ * T_;                                // 1 MB
  __hip_bfloat16* wp = (__hip_bfloat16*)((char*)(Cs + (size_t)B_ * T_));

  hipLaunchKernelGGL(af_pack, dim3((PK_TOT_ + 255) / 256), dim3(256), 0, stream,
                     eWih, eWhh, dWhh, f1W, wp);
  hipLaunchKernelGGL(af_encoder, dim3(NBE_), dim3(512), 0, stream,
                     x, h0, ebih, ebhh, aWq, abq, wp, hs, As, Cs);
  hipLaunchKernelGGL(af_decoder, dim3(NBD_), dim3(256), 0, stream,
                     x, dWih, dbih, dbhh, f1b, f2W, f2b, wp, hs, As, Cs,
                     (float*)d_out);
}

// Round 6
// 5637.294 us; speedup vs baseline: 1.2583x; 1.2583x over previous
//
#include <hip/hip_runtime.h>
#include <hip/hip_bf16.h>

// AttentiveFuturecaster R6.
//  - af_pack: weights -> MFMA-fragment order (1 chunk = 1 KB = one wave b128
//    load), bf16: eWhh | eWih | dWhh | f1W.
//  - af_encoder: 256 blocks x 256 thr (4 waves, 1 wave/SIMD, 512-VGPR budget),
//    BTE=8. eWhh fully REGISTER-RESIDENT (384 VGPR/wave, loaded once) -> no
//    per-step weight stream. eWih in LDS. h carried as bf16 hi+lo fused into
//    one 16-row MFMA A-tile (rows 0..7 hi / 8..15 lo, combine shfl_xor 32).
//    Emits hs (nontemporal) + rank-1 A/C attention tables.
//  - af_decoder: 512 blocks x 512 thr (8 waves, 2 waves/SIMD, 256-VGPR cap),
//    BTD=4. Two waves per batch row, column-split: hreg = u32[128] = 128 VGPR
//    (NO spill, vs R5's 256+spill). ctx phase zero memory traffic; softmax
//    weights broadcast via __shfl. dWhh/f1W streamed from L2 (packed frags).
// ws: hs bf16 [B,T,H] | As fp32 [B,T] | Cs fp32 [B,T] | packed weights.

#define B_    2048
#define T_    128
#define F_    64
#define H_    256
#define OUT_  32
#define BTE_  8
#define BTD_  4
#define NBE_  (B_ / BTE_)   // 256
#define NBD_  (B_ / BTD_)   // 512
#define HSTR_ 264
#define XSTR_ 72

// packed blob section offsets (bf16 elements)
#define PK_EHH_ 0
#define PK_EIH_ 196608
#define PK_DHH_ 245760
#define PK_F1_  442368
#define PK_TOT_ 507904
#define WIH_ELEMS_ 49152   // 3*H*F

typedef __attribute__((ext_vector_type(8))) short bf16x8;
typedef __attribute__((ext_vector_type(4))) float f32x4;
typedef unsigned long long u64;

__device__ __forceinline__ f32x4 mfma16(bf16x8 a, bf16x8 b, f32x4 c) {
  return __builtin_amdgcn_mfma_f32_16x16x32_bf16(a, b, c, 0, 0, 0);
}
__device__ __forceinline__ float sigm_(float x) { return 1.0f / (1.0f + __expf(-x)); }
__device__ __forceinline__ float tanh_(float x) {
  x = fminf(15.0f, fmaxf(-15.0f, x));
  float e = __expf(2.0f * x);
  return (e - 1.0f) / (e + 1.0f);
}
__device__ __forceinline__ unsigned short f2bf_(float f) {
  unsigned u = __float_as_uint(f);
  return (unsigned short)((u + 0x7FFFu + ((u >> 16) & 1u)) >> 16);
}
__device__ __forceinline__ float bf2f_(unsigned short s) {
  return __uint_as_float(((unsigned)s) << 16);
}
__device__ __forceinline__ float bfl_(const __hip_bfloat16* p) {
  return __bfloat162float(*p);
}

// ---------------- weight repack: fragment-ordered ----------------
__global__ __launch_bounds__(256) void af_pack(
    const float* __restrict__ eWih, const float* __restrict__ eWhh,
    const float* __restrict__ dWhh, const float* __restrict__ f1W,
    __hip_bfloat16* __restrict__ wb) {
  int i = blockIdx.x * blockDim.x + threadIdx.x;
  if (i >= PK_TOT_) return;
  float v;
  if (i < PK_EIH_) {                      // eWhh: chunk=(gm*16+c)*8+kk
    int q = i, j = q & 7, lane = (q >> 3) & 63, chunk = q >> 9;
    int kk = chunk & 7, c = (chunk >> 3) & 15, gm = chunk >> 7;
    int l16 = lane & 15, quad = lane >> 4;
    v = eWhh[(size_t)(gm * H_ + c * 16 + l16) * H_ + kk * 32 + quad * 8 + j];
  } else if (i < PK_DHH_) {               // eWih: chunk=(gm*16+c)*2+kk
    int q = i - PK_EIH_, j = q & 7, lane = (q >> 3) & 63, chunk = q >> 9;
    int kk = chunk & 1, c = (chunk >> 1) & 15, gm = chunk >> 5;
    int l16 = lane & 15, quad = lane >> 4;
    v = eWih[(size_t)(gm * H_ + c * 16 + l16) * F_ + kk * 32 + quad * 8 + j];
  } else if (i < PK_F1_) {                // dWhh
    int q = i - PK_DHH_, j = q & 7, lane = (q >> 3) & 63, chunk = q >> 9;
    int kk = chunk & 7, c = (chunk >> 3) & 15, gm = chunk >> 7;
    int l16 = lane & 15, quad = lane >> 4;
    v = dWhh[(size_t)(gm * H_ + c * 16 + l16) * H_ + kk * 32 + quad * 8 + j];
  } else {                                // f1W: chunk=c*8+kk
    int q = i - PK_F1_, j = q & 7, lane = (q >> 3) & 63, chunk = q >> 9;
    int kk = chunk & 7, c = chunk >> 3;
    int l16 = lane & 15, quad = lane >> 4;
    v = f1W[(size_t)(c * 16 + l16) * H_ + kk * 32 + quad * 8 + j];
  }
  wb[i] = __float2bfloat16(v);
}

// ============================ ENCODER ============================
__global__ __launch_bounds__(256, 1) void af_encoder(
    const float* __restrict__ x,
    const float* __restrict__ h0,
    const float* __restrict__ ebih,
    const float* __restrict__ ebhh,
    const float* __restrict__ aWq,
    const float* __restrict__ abq,
    const __hip_bfloat16* __restrict__ wp,
    __hip_bfloat16* __restrict__ hs,
    float* __restrict__ As,
    float* __restrict__ Cs)
{
  __shared__ __hip_bfloat16 s_wih[WIH_ELEMS_];   // 96 KB: eWih packed frags
  __shared__ __hip_bfloat16 sh[16 * HSTR_];      // rows 0..7 h-hi, 8..15 h-lo
  __shared__ __hip_bfloat16 sx[2][16 * XSTR_];   // rows 0..7 x-hi, 8..15 x-lo
  __shared__ float s_ebr[H_], s_ebz[H_], s_ebin[H_], s_ebhn[H_];
  __shared__ float s_wq[H_], s_bq[H_];

  const int tid  = threadIdx.x;
  const int b0   = blockIdx.x * BTE_;
  const int lane = tid & 63;
  const int wid  = tid >> 6;    // 0..3
  const int quad = lane >> 4;
  const int l16  = lane & 15;

  // prologue: constants, Wih->LDS, h0, x(t=0)
  s_ebr[tid]  = ebih[tid]          + ebhh[tid];
  s_ebz[tid]  = ebih[H_ + tid]     + ebhh[H_ + tid];
  s_ebin[tid] = ebih[2 * H_ + tid];
  s_ebhn[tid] = ebhh[2 * H_ + tid];
  s_wq[tid]   = aWq[tid] * 0.0625f;
  s_bq[tid]   = abq[tid] * 0.0625f;
  for (int i = tid; i < WIH_ELEMS_ / 4; i += 256)
    ((u64*)s_wih)[i] = ((const u64*)(wp + PK_EIH_))[i];
  {
    const int row = tid >> 5;          // 0..7
    const int c8  = (tid & 31) * 8;    // 0..248
    const float* hp = h0 + (size_t)(b0 + row) * H_ + c8;
    float4 v0 = *(const float4*)hp;
    float4 v1 = *(const float4*)(hp + 4);
    float vv[8] = {v0.x, v0.y, v0.z, v0.w, v1.x, v1.y, v1.z, v1.w};
#pragma unroll
    for (int j = 0; j < 8; ++j) {
      unsigned short hb = f2bf_(vv[j]);
      sh[row * HSTR_ + c8 + j]       = __float2bfloat16(vv[j]);
      sh[(row + 8) * HSTR_ + c8 + j] = __float2bfloat16(vv[j] - bf2f_(hb));
    }
    const int c2 = (tid & 31) * 2;
    float2 xv = *(const float2*)(x + ((size_t)(b0 + row) * T_) * F_ + c2);
    unsigned short xh0 = f2bf_(xv.x), xh1 = f2bf_(xv.y);
    sx[0][row * XSTR_ + c2]           = __float2bfloat16(xv.x);
    sx[0][row * XSTR_ + c2 + 1]       = __float2bfloat16(xv.y);
    sx[0][(row + 8) * XSTR_ + c2]     = __float2bfloat16(xv.x - bf2f_(xh0));
    sx[0][(row + 8) * XSTR_ + c2 + 1] = __float2bfloat16(xv.y - bf2f_(xh1));
  }
  __syncthreads();

  // eWhh -> registers: this wave's 4 column-blocks, all 3 gates (384 VGPR)
  bf16x8 wr[4][8], wz[4][8], wn[4][8];
#pragma unroll
  for (int s = 0; s < 4; ++s) {
    const int c = wid * 4 + s;
#pragma unroll
    for (int kk = 0; kk < 8; ++kk) {
      wr[s][kk] = *(const bf16x8*)(wp + PK_EHH_ + (size_t)((c)      * 8 + kk) * 512 + lane * 8);
      wz[s][kk] = *(const bf16x8*)(wp + PK_EHH_ + (size_t)((16 + c) * 8 + kk) * 512 + lane * 8);
      wn[s][kk] = *(const bf16x8*)(wp + PK_EHH_ + (size_t)((32 + c) * 8 + kk) * 512 + lane * 8);
    }
  }

#pragma unroll 1
  for (int t = 0; t < T_; ++t) {
    const int cur = t & 1, nxt = cur ^ 1;

    // phase 1: preload fused hi/lo h-fragments; prefetch x(t+1)
    bf16x8 ah[8];
#pragma unroll
    for (int kk = 0; kk < 8; ++kk)
      ah[kk] = *(const bf16x8*)&sh[l16 * HSTR_ + kk * 32 + quad * 8];
    if (t + 1 < T_) {
      const int row = tid >> 5, c2 = (tid & 31) * 2;
      float2 xv = *(const float2*)(x + ((size_t)(b0 + row) * T_ + (t + 1)) * F_ + c2);
      unsigned short xh0 = f2bf_(xv.x), xh1 = f2bf_(xv.y);
      sx[nxt][row * XSTR_ + c2]           = __float2bfloat16(xv.x);
      sx[nxt][row * XSTR_ + c2 + 1]       = __float2bfloat16(xv.y);
      sx[nxt][(row + 8) * XSTR_ + c2]     = __float2bfloat16(xv.x - bf2f_(xh0));
      sx[nxt][(row + 8) * XSTR_ + c2 + 1] = __float2bfloat16(xv.y - bf2f_(xh1));
    }
    __syncthreads();

    // phase 2: MFMA (reg weights) + gate math + in-place h update
#pragma unroll
    for (int s = 0; s < 4; ++s) {
      const int c = wid * 4 + s;
      const int g = c * 16 + l16;
      f32x4 ar = {0.f, 0.f, 0.f, 0.f}, az = ar, ani = ar, anh = ar;
#pragma unroll
      for (int kk = 0; kk < 8; ++kk) {
        ar  = mfma16(ah[kk], wr[s][kk], ar);
        az  = mfma16(ah[kk], wz[s][kk], az);
        anh = mfma16(ah[kk], wn[s][kk], anh);
      }
#pragma unroll
      for (int kk = 0; kk < 2; ++kk) {
        bf16x8 axf = *(const bf16x8*)&sx[cur][l16 * XSTR_ + kk * 32 + quad * 8];
        bf16x8 qr = *(const bf16x8*)&s_wih[((c)      * 2 + kk) * 512 + lane * 8];
        bf16x8 qz = *(const bf16x8*)&s_wih[((16 + c) * 2 + kk) * 512 + lane * 8];
        bf16x8 qn = *(const bf16x8*)&s_wih[((32 + c) * 2 + kk) * 512 + lane * 8];
        ar  = mfma16(axf, qr, ar);
        az  = mfma16(axf, qz, az);
        ani = mfma16(axf, qn, ani);
      }
#pragma unroll
      for (int i = 0; i < 4; ++i) {
        float vr = ar[i]  + __shfl_xor(ar[i],  32);
        float vz = az[i]  + __shfl_xor(az[i],  32);
        float vi = ani[i] + __shfl_xor(ani[i], 32);
        float vh = anh[i] + __shfl_xor(anh[i], 32);
        if (quad < 2) {
          const int m = quad * 4 + i;   // batch row 0..7
          float r = sigm_(vr + s_ebr[g]);
          float z = sigm_(vz + s_ebz[g]);
          float n = tanh_(vi + s_ebin[g] + r * (vh + s_ebhn[g]));
          float hold = bfl_(&sh[m * HSTR_ + g]) + bfl_(&sh[(m + 8) * HSTR_ + g]);
          float hn = (1.0f - z) * n + z * hold;
          unsigned short hb = f2bf_(hn);
          sh[m * HSTR_ + g]       = __float2bfloat16(hn);
          sh[(m + 8) * HSTR_ + g] = __float2bfloat16(hn - bf2f_(hb));
        }
      }
    }
    __syncthreads();

    // phase 3: hs store (nontemporal) + A/C tables (2 rows per wave)
#pragma unroll
    for (int rr = 0; rr < 2; ++rr) {
      const int row = wid * 2 + rr;
      const int c4  = lane * 4;
      u64 hv = *(const u64*)&sh[row * HSTR_ + c4];
      __builtin_nontemporal_store(
          hv, (u64*)(hs + ((size_t)(b0 + row) * T_ + t) * H_ + c4));
      float pa = 0.f, pc = 0.f;
#pragma unroll
      for (int j = 0; j < 4; ++j) {
        float hvf = bfl_(&sh[row * HSTR_ + c4 + j]) +
                    bfl_(&sh[(row + 8) * HSTR_ + c4 + j]);
        pa = fmaf(hvf, s_wq[c4 + j], pa);
        pc = fmaf(hvf, s_bq[c4 + j], pc);
      }
#pragma unroll
      for (int off = 32; off >= 1; off >>= 1) {
        pa += __shfl_xor(pa, off);
        pc += __shfl_xor(pc, off);
      }
      if (lane == 0) {
        As[(size_t)(b0 + row) * T_ + t] = pa;
        Cs[(size_t)(b0 + row) * T_ + t] = pc;
      }
    }
  }
}

// ============================ DECODER ============================
__global__ __launch_bounds__(512, 2) void af_decoder(
    const float* __restrict__ x,
    const float* __restrict__ dWih,
    const float* __restrict__ dbih,
    const float* __restrict__ dbhh,
    const float* __restrict__ f1b,
    const float* __restrict__ f2W,
    const float* __restrict__ f2b,
    const __hip_bfloat16* __restrict__ wp,
    const __hip_bfloat16* __restrict__ hs,
    const float* __restrict__ As,
    const float* __restrict__ Cs,
    float* __restrict__ dout)
{
  __shared__ __hip_bfloat16 ctx_t[16 * HSTR_];  // rows 0..3 hi, 4..7 lo, 8..15 zero
  __shared__ __hip_bfloat16 hd_t[16 * HSTR_];   // same packing
  __shared__ float ctxf[4 * 260];
  __shared__ float f1f[4 * 260];
  __shared__ float sA[4 * T_], sC[4 * T_];
  __shared__ float s_dbr[H_], s_dbz[H_], s_dbin[H_], s_dbhn[H_];
  __shared__ float s_dwih[3 * H_];
  __shared__ float s_f1b[H_], s_f2w[H_];
  __shared__ float s_f2b, s_prev[BTD_];

  const int tid   = threadIdx.x;
  const int b0    = blockIdx.x * BTD_;
  const int lane  = tid & 63;
  const int wv    = tid >> 6;    // 0..7
  const int drow  = wv >> 1;     // 0..3: batch row
  const int chalf = wv & 1;      // column half (0: cols 0..127, 1: 128..255)
  const int quad  = lane >> 4;
  const int l16   = lane & 15;

  if (tid < H_) {
    s_dbr[tid]  = dbih[tid]          + dbhh[tid];
    s_dbz[tid]  = dbih[H_ + tid]     + dbhh[H_ + tid];
    s_dbin[tid] = dbih[2 * H_ + tid];
    s_dbhn[tid] = dbhh[2 * H_ + tid];
    s_f1b[tid]  = f1b[tid];
    s_f2w[tid]  = f2W[tid];
  }
  for (int i = tid; i < 3 * H_; i += 512) s_dwih[i] = dWih[i];
  sA[tid] = As[(size_t)(b0 + (tid >> 7)) * T_ + (tid & 127)];
  sC[tid] = Cs[(size_t)(b0 + (tid >> 7)) * T_ + (tid & 127)];
  if (tid < BTD_) s_prev[tid] = x[((size_t)(b0 + tid) * T_ + (T_ - 1)) * F_];
  if (tid == 0) s_f2b = f2b[0];
  for (int i = tid; i < 8 * HSTR_; i += 512) {
    ctx_t[8 * HSTR_ + i] = __float2bfloat16(0.f);
    hd_t[8 * HSTR_ + i]  = __float2bfloat16(0.f);
  }

  // this wave's 128-column half of its row's hs history: 128 VGPRs
  unsigned hreg[T_];
  {
    const int c0 = chalf * 128 + lane * 2;
    const __hip_bfloat16* hp = hs + (size_t)(b0 + drow) * T_ * H_ + c0;
#pragma unroll
    for (int t = 0; t < T_; ++t)
      hreg[t] = __builtin_nontemporal_load((const unsigned*)(hp + (size_t)t * H_));
  }
  __syncthreads();

#pragma unroll 1
  for (int s = 0; s < OUT_; ++s) {
    // P1: softmax over T, in-registers (both waves of a row compute it)
    float w0, w1;
    {
      const float pv = s_prev[drow];
      float sc0 = fmaf(pv, sA[drow * T_ + lane],      sC[drow * T_ + lane]);
      float sc1 = fmaf(pv, sA[drow * T_ + lane + 64], sC[drow * T_ + lane + 64]);
      float mx = fmaxf(sc0, sc1);
#pragma unroll
      for (int off = 32; off >= 1; off >>= 1) mx = fmaxf(mx, __shfl_xor(mx, off));
      float e0 = __expf(sc0 - mx), e1 = __expf(sc1 - mx);
      float ss = e0 + e1;
#pragma unroll
      for (int off = 32; off >= 1; off >>= 1) ss += __shfl_xor(ss, off);
      const float inv = 1.0f / ss;
      w0 = e0 * inv; w1 = e1 * inv;
    }
    // P2: ctx from registers (zero memory traffic; w broadcast via shfl)
    {
      float a0 = 0.f, a1 = 0.f;
#pragma unroll
      for (int t = 0; t < 64; ++t) {
        const float wt = __shfl(w0, t);
        const unsigned hv = hreg[t];
        a0 = fmaf(wt, __uint_as_float(hv << 16),         a0);
        a1 = fmaf(wt, __uint_as_float(hv & 0xFFFF0000u), a1);
      }
#pragma unroll
      for (int t = 0; t < 64; ++t) {
        const float wt = __shfl(w1, t);
        const unsigned hv = hreg[64 + t];
        a0 = fmaf(wt, __uint_as_float(hv << 16),         a0);
        a1 = fmaf(wt, __uint_as_float(hv & 0xFFFF0000u), a1);
      }
      const int c0 = chalf * 128 + lane * 2;
      ctxf[drow * 260 + c0]     = a0;
      ctxf[drow * 260 + c0 + 1] = a1;
      unsigned short b0b = f2bf_(a0), b1b = f2bf_(a1);
      ctx_t[drow * HSTR_ + c0]           = __float2bfloat16(a0);
      ctx_t[drow * HSTR_ + c0 + 1]       = __float2bfloat16(a1);
      ctx_t[(drow + 4) * HSTR_ + c0]     = __float2bfloat16(a0 - bf2f_(b0b));
      ctx_t[(drow + 4) * HSTR_ + c0 + 1] = __float2bfloat16(a1 - bf2f_(b1b));
    }
    __syncthreads();

    // P3: decoder GRU (MFMA, hi/lo fused rows 0..3/4..7; weights from L2)
    {
      bf16x8 ah[8];
#pragma unroll
      for (int kk = 0; kk < 8; ++kk)
        ah[kk] = *(const bf16x8*)&ctx_t[l16 * HSTR_ + kk * 32 + quad * 8];
#pragma unroll
      for (int s3 = 0; s3 < 2; ++s3) {
        const int c = wv * 2 + s3;
        const int g = c * 16 + l16;
        f32x4 ar = {0.f, 0.f, 0.f, 0.f}, az = ar, anh = ar;
#pragma unroll
        for (int kk = 0; kk < 8; ++kk) {
          bf16x8 br = *(const bf16x8*)(wp + PK_DHH_ + (size_t)((c)      * 8 + kk) * 512 + lane * 8);
          bf16x8 bz = *(const bf16x8*)(wp + PK_DHH_ + (size_t)((16 + c) * 8 + kk) * 512 + lane * 8);
          bf16x8 bn = *(const bf16x8*)(wp + PK_DHH_ + (size_t)((32 + c) * 8 + kk) * 512 + lane * 8);
          ar  = mfma16(ah[kk], br, ar);
          az  = mfma16(ah[kk], bz, az);
          anh = mfma16(ah[kk], bn, anh);
        }
#pragma unroll
        for (int i = 0; i < 4; ++i) {
          float vr = ar[i]  + __shfl_xor(ar[i],  16);
          float vz = az[i]  + __shfl_xor(az[i],  16);
          float vh = anh[i] + __shfl_xor(anh[i], 16);
          if (quad == 0) {
            const int m = i;
            const float pv = s_prev[m];
            float r = sigm_(vr + fmaf(pv, s_dwih[g],      s_dbr[g]));
            float z = sigm_(vz + fmaf(pv, s_dwih[H_ + g], s_dbz[g]));
            float n = tanh_(fmaf(pv, s_dwih[2 * H_ + g], s_dbin[g]) +
                            r * (vh + s_dbhn[g]));
            float hd = (1.0f - z) * n + z * ctxf[m * 260 + g];
            unsigned short hb = f2bf_(hd);
            hd_t[m * HSTR_ + g]       = __float2bfloat16(hd);
            hd_t[(m + 4) * HSTR_ + g] = __float2bfloat16(hd - bf2f_(hb));
          }
        }
      }
    }
    __syncthreads();

    // P4: fc1 + relu (MFMA, hi/lo fused)
    {
      bf16x8 ad[8];
#pragma unroll
      for (int kk = 0; kk < 8; ++kk)
        ad[kk] = *(const bf16x8*)&hd_t[l16 * HSTR_ + kk * 32 + quad * 8];
#pragma unroll
      for (int s3 = 0; s3 < 2; ++s3) {
        const int c = wv * 2 + s3;
        const int jc = c * 16 + l16;
        f32x4 a1 = {0.f, 0.f, 0.f, 0.f};
#pragma unroll
        for (int kk = 0; kk < 8; ++kk)
          a1 = mfma16(ad[kk],
                      *(const bf16x8*)(wp + PK_F1_ + (size_t)((c) * 8 + kk) * 512 + lane * 8),
                      a1);
#pragma unroll
        for (int i = 0; i < 4; ++i) {
          float v = a1[i] + __shfl_xor(a1[i], 16);
          if (quad == 0)
            f1f[i * 260 + jc] = fmaxf(v + s_f1b[jc], 0.0f);
        }
      }
    }
    __syncthreads();

    // P5: fc2 dot -> out, update prev (chalf==0 wave per row)
    if (chalf == 0) {
      const int c4 = lane * 4;
      float p = 0.f;
#pragma unroll
      for (int j = 0; j < 4; ++j)
        p = fmaf(f1f[drow * 260 + c4 + j], s_f2w[c4 + j], p);
#pragma unroll
      for (int off = 32; off >= 1; off >>= 1) p += __shfl_xor(p, off);
      if (lane == 0) {
        float o = p + s_f2b;
        s_prev[drow] = o;
        dout[(size_t)(b0 + drow) * OUT_ + s] = o;
      }
    }
    __syncthreads();
  }
}

extern "C" void kernel_launch(void* const* d_in, const int* in_sizes, int n_in,
                              void* d_out, int out_size, void* d_ws, size_t ws_size,
                              hipStream_t stream) {
  (void)in_sizes; (void)n_in; (void)out_size; (void)ws_size;
  const float* x    = (const float*)d_in[0];
  const float* h0   = (const float*)d_in[1];
  const float* eWih = (const float*)d_in[2];
  const float* eWhh = (const float*)d_in[3];
  const float* ebih = (const float*)d_in[4];
  const float* ebhh = (const float*)d_in[5];
  const float* dWih = (const float*)d_in[6];
  const float* dWhh = (const float*)d_in[7];
  const float* dbih = (const float*)d_in[8];
  const float* dbhh = (const float*)d_in[9];
  const float* aWq  = (const float*)d_in[10];
  const float* abq  = (const float*)d_in[11];
  const float* f1W  = (const float*)d_in[12];
  const float* f1b  = (const float*)d_in[13];
  const float* f2W  = (const float*)d_in[14];
  const float* f2b  = (const float*)d_in[15];

  char* wsb = (char*)d_ws;
  __hip_bfloat16* hs = (__hip_bfloat16*)wsb;                       // 134,217,728 B
  float* As = (float*)(wsb + (size_t)B_ * T_ * H_ * 2);            // 1 MB
  float* Cs = As + (size_t)B_ * T_;                                // 1 MB
  __hip_bfloat16* wp = (__hip_bfloat16*)((char*)(Cs + (size_t)B_ * T_));

  hipLaunchKernelGGL(af_pack, dim3((PK_TOT_ + 255) / 256), dim3(256), 0, stream,
                     eWih, eWhh, dWhh, f1W, wp);
  hipLaunchKernelGGL(af_encoder, dim3(NBE_), dim3(256), 0, stream,
                     x, h0, ebih, ebhh, aWq, abq, wp, hs, As, Cs);
  hipLaunchKernelGGL(af_decoder, dim3(NBD_), dim3(512), 0, stream,
                     x, dWih, dbih, dbhh, f1b, f2W, f2b, wp, hs, As, Cs,
                     (float*)d_out);
}

// Round 7
// 5395.269 us; speedup vs baseline: 1.3147x; 1.0449x over previous
//
#include <hip/hip_runtime.h>
#include <hip/hip_bf16.h>

// AttentiveFuturecaster R7.
// Empirical finding (R5/R6 VGPR counters): __launch_bounds__ 2nd arg acts as
// CUDA-style MIN BLOCKS PER CU on this toolchain: (512,2) gave a 128-VGPR cap
// (16 waves/CU) and spilled hreg. Use (512,1) -> 256-VGPR cap.
//  - af_pack: weights -> MFMA-fragment order (1 chunk = 1 KB = one wave b128).
//  - af_encoder: 128 blocks x 512 thr, BTE=16 (halves aggregate L2 weight
//    traffic vs BTE=8: bytes/block/step are fixed). Streams packed eWhh/eWih
//    from L2; h carried as bf16 hi+lo, folded via TWO MFMAs per chunk into one
//    fp32 accumulator (M=16 real batch rows). Emits hs + rank-1 A/C tables.
//  - af_decoder: 512 blocks x 512 thr, BTD=4, (512,1) -> cap 256. Two waves
//    per row hold the row's hs history column-split in u32 hreg[128] (128
//    VGPR) -> ctx phase is zero-memory-traffic. dWhh/f1W streamed from L2.
// ws: hs bf16 [B,T,H] | As fp32 [B,T] | Cs fp32 [B,T] | packed weights.

#define B_    2048
#define T_    128
#define F_    64
#define H_    256
#define OUT_  32
#define BTE_  16
#define BTD_  4
#define NBE_  (B_ / BTE_)   // 128
#define NBD_  (B_ / BTD_)   // 512
#define HSTR_ 264
#define XSTR_ 72

// packed blob section offsets (bf16 elements)
#define PK_EHH_ 0
#define PK_EIH_ 196608
#define PK_DHH_ 245760
#define PK_F1_  442368
#define PK_TOT_ 507904

typedef __attribute__((ext_vector_type(8))) short bf16x8;
typedef __attribute__((ext_vector_type(4))) float f32x4;
typedef unsigned long long u64;

__device__ __forceinline__ f32x4 mfma16(bf16x8 a, bf16x8 b, f32x4 c) {
  return __builtin_amdgcn_mfma_f32_16x16x32_bf16(a, b, c, 0, 0, 0);
}
__device__ __forceinline__ float sigm_(float x) { return 1.0f / (1.0f + __expf(-x)); }
__device__ __forceinline__ float tanh_(float x) {
  x = fminf(15.0f, fmaxf(-15.0f, x));
  float e = __expf(2.0f * x);
  return (e - 1.0f) / (e + 1.0f);
}
__device__ __forceinline__ unsigned short f2bf_(float f) {
  unsigned u = __float_as_uint(f);
  return (unsigned short)((u + 0x7FFFu + ((u >> 16) & 1u)) >> 16);
}
__device__ __forceinline__ float bf2f_(unsigned short s) {
  return __uint_as_float(((unsigned)s) << 16);
}
__device__ __forceinline__ float bfl_(const __hip_bfloat16* p) {
  return __bfloat162float(*p);
}

// ---------------- weight repack: fragment-ordered ----------------
__global__ __launch_bounds__(256) void af_pack(
    const float* __restrict__ eWih, const float* __restrict__ eWhh,
    const float* __restrict__ dWhh, const float* __restrict__ f1W,
    __hip_bfloat16* __restrict__ wb) {
  int i = blockIdx.x * blockDim.x + threadIdx.x;
  if (i >= PK_TOT_) return;
  float v;
  if (i < PK_EIH_) {                      // eWhh: chunk=(gm*16+c)*8+kk
    int q = i, j = q & 7, lane = (q >> 3) & 63, chunk = q >> 9;
    int kk = chunk & 7, c = (chunk >> 3) & 15, gm = chunk >> 7;
    int l16 = lane & 15, quad = lane >> 4;
    v = eWhh[(size_t)(gm * H_ + c * 16 + l16) * H_ + kk * 32 + quad * 8 + j];
  } else if (i < PK_DHH_) {               // eWih: chunk=(gm*16+c)*2+kk
    int q = i - PK_EIH_, j = q & 7, lane = (q >> 3) & 63, chunk = q >> 9;
    int kk = chunk & 1, c = (chunk >> 1) & 15, gm = chunk >> 5;
    int l16 = lane & 15, quad = lane >> 4;
    v = eWih[(size_t)(gm * H_ + c * 16 + l16) * F_ + kk * 32 + quad * 8 + j];
  } else if (i < PK_F1_) {                // dWhh
    int q = i - PK_DHH_, j = q & 7, lane = (q >> 3) & 63, chunk = q >> 9;
    int kk = chunk & 7, c = (chunk >> 3) & 15, gm = chunk >> 7;
    int l16 = lane & 15, quad = lane >> 4;
    v = dWhh[(size_t)(gm * H_ + c * 16 + l16) * H_ + kk * 32 + quad * 8 + j];
  } else {                                // f1W: chunk=c*8+kk
    int q = i - PK_F1_, j = q & 7, lane = (q >> 3) & 63, chunk = q >> 9;
    int kk = chunk & 7, c = chunk >> 3;
    int l16 = lane & 15, quad = lane >> 4;
    v = f1W[(size_t)(c * 16 + l16) * H_ + kk * 32 + quad * 8 + j];
  }
  wb[i] = __float2bfloat16(v);
}

// ============================ ENCODER ============================
__global__ __launch_bounds__(512, 1) void af_encoder(
    const float* __restrict__ x,
    const float* __restrict__ h0,
    const float* __restrict__ ebih,
    const float* __restrict__ ebhh,
    const float* __restrict__ aWq,
    const float* __restrict__ abq,
    const __hip_bfloat16* __restrict__ wp,
    __hip_bfloat16* __restrict__ hs,
    float* __restrict__ As,
    float* __restrict__ Cs)
{
  __shared__ __hip_bfloat16 sh[BTE_ * HSTR_];      // h hi (16 batch rows)
  __shared__ __hip_bfloat16 sl[BTE_ * HSTR_];      // h lo
  __shared__ __hip_bfloat16 sx[2][BTE_ * XSTR_];   // x hi (double buffer)
  __shared__ __hip_bfloat16 sxl[2][BTE_ * XSTR_];  // x lo
  __shared__ float s_ebr[H_], s_ebz[H_], s_ebin[H_], s_ebhn[H_];
  __shared__ float s_wq[H_], s_bq[H_];

  const int tid  = threadIdx.x;
  const int b0   = blockIdx.x * BTE_;
  const int lane = tid & 63;
  const int wid  = tid >> 6;    // 0..7
  const int quad = lane >> 4;
  const int l16  = lane & 15;
  const int srow = tid >> 5;    // 0..15 (staging row)
  const int sc   = tid & 31;    // 0..31

  if (tid < H_) {
    s_ebr[tid]  = ebih[tid]          + ebhh[tid];
    s_ebz[tid]  = ebih[H_ + tid]     + ebhh[H_ + tid];
    s_ebin[tid] = ebih[2 * H_ + tid];
    s_ebhn[tid] = ebhh[2 * H_ + tid];
    s_wq[tid]   = aWq[tid] * 0.0625f;
    s_bq[tid]   = abq[tid] * 0.0625f;
  }
  {
    const int c8 = sc * 8;
    const float* hp = h0 + (size_t)(b0 + srow) * H_ + c8;
    float4 v0 = *(const float4*)hp;
    float4 v1 = *(const float4*)(hp + 4);
    float vv[8] = {v0.x, v0.y, v0.z, v0.w, v1.x, v1.y, v1.z, v1.w};
#pragma unroll
    for (int j = 0; j < 8; ++j) {
      unsigned short hb = f2bf_(vv[j]);
      sh[srow * HSTR_ + c8 + j] = __float2bfloat16(vv[j]);
      sl[srow * HSTR_ + c8 + j] = __float2bfloat16(vv[j] - bf2f_(hb));
    }
    const int c2 = sc * 2;
    float2 xv = *(const float2*)(x + ((size_t)(b0 + srow) * T_) * F_ + c2);
    unsigned short xh0 = f2bf_(xv.x), xh1 = f2bf_(xv.y);
    sx[0][srow * XSTR_ + c2]      = __float2bfloat16(xv.x);
    sx[0][srow * XSTR_ + c2 + 1]  = __float2bfloat16(xv.y);
    sxl[0][srow * XSTR_ + c2]     = __float2bfloat16(xv.x - bf2f_(xh0));
    sxl[0][srow * XSTR_ + c2 + 1] = __float2bfloat16(xv.y - bf2f_(xh1));
  }
  __syncthreads();

#pragma unroll 1
  for (int t = 0; t < T_; ++t) {
    const int cur = t & 1, nxt = cur ^ 1;

    // phase 1: preload h/x fragments; prefetch x(t+1)
    bf16x8 ah[8], al[8], axh[2], axl[2];
#pragma unroll
    for (int kk = 0; kk < 8; ++kk) {
      ah[kk] = *(const bf16x8*)&sh[l16 * HSTR_ + kk * 32 + quad * 8];
      al[kk] = *(const bf16x8*)&sl[l16 * HSTR_ + kk * 32 + quad * 8];
    }
#pragma unroll
    for (int kk = 0; kk < 2; ++kk) {
      axh[kk] = *(const bf16x8*)&sx[cur][l16 * XSTR_ + kk * 32 + quad * 8];
      axl[kk] = *(const bf16x8*)&sxl[cur][l16 * XSTR_ + kk * 32 + quad * 8];
    }
    if (t + 1 < T_) {
      const int c2 = sc * 2;
      float2 xv = *(const float2*)(x + ((size_t)(b0 + srow) * T_ + (t + 1)) * F_ + c2);
      unsigned short xh0 = f2bf_(xv.x), xh1 = f2bf_(xv.y);
      sx[nxt][srow * XSTR_ + c2]      = __float2bfloat16(xv.x);
      sx[nxt][srow * XSTR_ + c2 + 1]  = __float2bfloat16(xv.y);
      sxl[nxt][srow * XSTR_ + c2]     = __float2bfloat16(xv.x - bf2f_(xh0));
      sxl[nxt][srow * XSTR_ + c2 + 1] = __float2bfloat16(xv.y - bf2f_(xh1));
    }
    __syncthreads();

    // phase 2: MFMA (streamed packed weights, hi+lo folded) + gates + update
#pragma unroll
    for (int s2 = 0; s2 < 2; ++s2) {
      const int c = wid * 2 + s2;
      const int g = c * 16 + l16;
      const __hip_bfloat16* wb_ = wp + PK_EHH_ + (size_t)(c * 8) * 512 + lane * 8;
      f32x4 ar = {0.f, 0.f, 0.f, 0.f}, az = ar, ani = ar, anh = ar;
#pragma unroll
      for (int kk = 0; kk < 8; ++kk) {
        bf16x8 br = *(const bf16x8*)(wb_ + kk * 512);
        bf16x8 bz = *(const bf16x8*)(wb_ + 65536 + kk * 512);
        bf16x8 bn = *(const bf16x8*)(wb_ + 131072 + kk * 512);
        ar  = mfma16(al[kk], br, ar);  ar  = mfma16(ah[kk], br, ar);
        az  = mfma16(al[kk], bz, az);  az  = mfma16(ah[kk], bz, az);
        anh = mfma16(al[kk], bn, anh); anh = mfma16(ah[kk], bn, anh);
      }
      const __hip_bfloat16* qb_ = wp + PK_EIH_ + (size_t)(c * 2) * 512 + lane * 8;
#pragma unroll
      for (int kk = 0; kk < 2; ++kk) {
        bf16x8 br = *(const bf16x8*)(qb_ + kk * 512);
        bf16x8 bz = *(const bf16x8*)(qb_ + 16384 + kk * 512);
        bf16x8 bn = *(const bf16x8*)(qb_ + 32768 + kk * 512);
        ar  = mfma16(axl[kk], br, ar);  ar  = mfma16(axh[kk], br, ar);
        az  = mfma16(axl[kk], bz, az);  az  = mfma16(axh[kk], bz, az);
        ani = mfma16(axl[kk], bn, ani); ani = mfma16(axh[kk], bn, ani);
      }
      const float br_ = s_ebr[g], bz_ = s_ebz[g], bi_ = s_ebin[g], bh_ = s_ebhn[g];
#pragma unroll
      for (int i = 0; i < 4; ++i) {
        const int m = quad * 4 + i;   // batch row 0..15
        float r = sigm_(ar[i] + br_);
        float z = sigm_(az[i] + bz_);
        float n = tanh_(ani[i] + bi_ + r * (anh[i] + bh_));
        float hold = bfl_(&sh[m * HSTR_ + g]) + bfl_(&sl[m * HSTR_ + g]);
        float hn = (1.0f - z) * n + z * hold;
        unsigned short hb = f2bf_(hn);
        sh[m * HSTR_ + g] = __float2bfloat16(hn);
        sl[m * HSTR_ + g] = __float2bfloat16(hn - bf2f_(hb));
      }
    }
    __syncthreads();

    // phase 3: hs store (nontemporal) + A/C tables (2 rows per wave)
#pragma unroll
    for (int rr = 0; rr < 2; ++rr) {
      const int row = wid * 2 + rr;
      const int c4  = lane * 4;
      u64 hv = *(const u64*)&sh[row * HSTR_ + c4];
      __builtin_nontemporal_store(
          hv, (u64*)(hs + ((size_t)(b0 + row) * T_ + t) * H_ + c4));
      float pa = 0.f, pc = 0.f;
#pragma unroll
      for (int j = 0; j < 4; ++j) {
        float hvf = bfl_(&sh[row * HSTR_ + c4 + j]) + bfl_(&sl[row * HSTR_ + c4 + j]);
        pa = fmaf(hvf, s_wq[c4 + j], pa);
        pc = fmaf(hvf, s_bq[c4 + j], pc);
      }
#pragma unroll
      for (int off = 32; off >= 1; off >>= 1) {
        pa += __shfl_xor(pa, off);
        pc += __shfl_xor(pc, off);
      }
      if (lane == 0) {
        As[(size_t)(b0 + row) * T_ + t] = pa;
        Cs[(size_t)(b0 + row) * T_ + t] = pc;
      }
    }
  }
}

// ============================ DECODER ============================
__global__ __launch_bounds__(512, 1) void af_decoder(
    const float* __restrict__ x,
    const float* __restrict__ dWih,
    const float* __restrict__ dbih,
    const float* __restrict__ dbhh,
    const float* __restrict__ f1b,
    const float* __restrict__ f2W,
    const float* __restrict__ f2b,
    const __hip_bfloat16* __restrict__ wp,
    const __hip_bfloat16* __restrict__ hs,
    const float* __restrict__ As,
    const float* __restrict__ Cs,
    float* __restrict__ dout)
{
  __shared__ __hip_bfloat16 ctx_t[16 * HSTR_];  // rows 0..3 hi, 4..7 lo, 8..15 zero
  __shared__ __hip_bfloat16 hd_t[16 * HSTR_];   // same packing
  __shared__ float ctxf[4 * 260];
  __shared__ float f1f[4 * 260];
  __shared__ float sA[4 * T_], sC[4 * T_];
  __shared__ float s_dbr[H_], s_dbz[H_], s_dbin[H_], s_dbhn[H_];
  __shared__ float s_dwih[3 * H_];
  __shared__ float s_f1b[H_], s_f2w[H_];
  __shared__ float s_f2b, s_prev[BTD_];

  const int tid   = threadIdx.x;
  const int b0    = blockIdx.x * BTD_;
  const int lane  = tid & 63;
  const int wv    = tid >> 6;    // 0..7
  const int drow  = wv >> 1;     // 0..3: batch row
  const int chalf = wv & 1;      // column half (0: cols 0..127, 1: 128..255)
  const int quad  = lane >> 4;
  const int l16   = lane & 15;

  if (tid < H_) {
    s_dbr[tid]  = dbih[tid]          + dbhh[tid];
    s_dbz[tid]  = dbih[H_ + tid]     + dbhh[H_ + tid];
    s_dbin[tid] = dbih[2 * H_ + tid];
    s_dbhn[tid] = dbhh[2 * H_ + tid];
    s_f1b[tid]  = f1b[tid];
    s_f2w[tid]  = f2W[tid];
  }
  for (int i = tid; i < 3 * H_; i += 512) s_dwih[i] = dWih[i];
  sA[tid] = As[(size_t)(b0 + (tid >> 7)) * T_ + (tid & 127)];
  sC[tid] = Cs[(size_t)(b0 + (tid >> 7)) * T_ + (tid & 127)];
  if (tid < BTD_) s_prev[tid] = x[((size_t)(b0 + tid) * T_ + (T_ - 1)) * F_];
  if (tid == 0) s_f2b = f2b[0];
  for (int i = tid; i < 8 * HSTR_; i += 512) {
    ctx_t[8 * HSTR_ + i] = __float2bfloat16(0.f);
    hd_t[8 * HSTR_ + i]  = __float2bfloat16(0.f);
  }

  // this wave's 128-column half of its row's hs history: 128 VGPRs
  unsigned hreg[T_];
  {
    const int c0 = chalf * 128 + lane * 2;
    const __hip_bfloat16* hp = hs + (size_t)(b0 + drow) * T_ * H_ + c0;
#pragma unroll
    for (int t = 0; t < T_; ++t)
      hreg[t] = __builtin_nontemporal_load((const unsigned*)(hp + (size_t)t * H_));
  }
  __syncthreads();

#pragma unroll 1
  for (int s = 0; s < OUT_; ++s) {
    // P1: softmax over T, in registers (both waves of a row compute it)
    float w0, w1;
    {
      const float pv = s_prev[drow];
      float sc0 = fmaf(pv, sA[drow * T_ + lane],      sC[drow * T_ + lane]);
      float sc1 = fmaf(pv, sA[drow * T_ + lane + 64], sC[drow * T_ + lane + 64]);
      float mx = fmaxf(sc0, sc1);
#pragma unroll
      for (int off = 32; off >= 1; off >>= 1) mx = fmaxf(mx, __shfl_xor(mx, off));
      float e0 = __expf(sc0 - mx), e1 = __expf(sc1 - mx);
      float ss = e0 + e1;
#pragma unroll
      for (int off = 32; off >= 1; off >>= 1) ss += __shfl_xor(ss, off);
      const float inv = 1.0f / ss;
      w0 = e0 * inv; w1 = e1 * inv;
    }
    // P2: ctx from registers (zero memory traffic; w broadcast via shfl)
    {
      float a0 = 0.f, a1 = 0.f;
#pragma unroll
      for (int t = 0; t < 64; ++t) {
        const float wt = __shfl(w0, t);
        const unsigned hv = hreg[t];
        a0 = fmaf(wt, __uint_as_float(hv << 16),         a0);
        a1 = fmaf(wt, __uint_as_float(hv & 0xFFFF0000u), a1);
      }
#pragma unroll
      for (int t = 0; t < 64; ++t) {
        const float wt = __shfl(w1, t);
        const unsigned hv = hreg[64 + t];
        a0 = fmaf(wt, __uint_as_float(hv << 16),         a0);
        a1 = fmaf(wt, __uint_as_float(hv & 0xFFFF0000u), a1);
      }
      const int c0 = chalf * 128 + lane * 2;
      ctxf[drow * 260 + c0]     = a0;
      ctxf[drow * 260 + c0 + 1] = a1;
      unsigned short b0b = f2bf_(a0), b1b = f2bf_(a1);
      ctx_t[drow * HSTR_ + c0]           = __float2bfloat16(a0);
      ctx_t[drow * HSTR_ + c0 + 1]       = __float2bfloat16(a1);
      ctx_t[(drow + 4) * HSTR_ + c0]     = __float2bfloat16(a0 - bf2f_(b0b));
      ctx_t[(drow + 4) * HSTR_ + c0 + 1] = __float2bfloat16(a1 - bf2f_(b1b));
    }
    __syncthreads();

    // P3: decoder GRU (MFMA, hi/lo fused rows 0..3/4..7; weights from L2)
    {
      bf16x8 ah[8];
#pragma unroll
      for (int kk = 0; kk < 8; ++kk)
        ah[kk] = *(const bf16x8*)&ctx_t[l16 * HSTR_ + kk * 32 + quad * 8];
#pragma unroll
      for (int s3 = 0; s3 < 2; ++s3) {
        const int c = wv * 2 + s3;
        const int g = c * 16 + l16;
        const __hip_bfloat16* wb_ = wp + PK_DHH_ + (size_t)(c * 8) * 512 + lane * 8;
        f32x4 ar = {0.f, 0.f, 0.f, 0.f}, az = ar, anh = ar;
#pragma unroll
        for (int kk = 0; kk < 8; ++kk) {
          bf16x8 br = *(const bf16x8*)(wb_ + kk * 512);
          bf16x8 bz = *(const bf16x8*)(wb_ + 65536 + kk * 512);
          bf16x8 bn = *(const bf16x8*)(wb_ + 131072 + kk * 512);
          ar  = mfma16(ah[kk], br, ar);
          az  = mfma16(ah[kk], bz, az);
          anh = mfma16(ah[kk], bn, anh);
        }
#pragma unroll
        for (int i = 0; i < 4; ++i) {
          float vr = ar[i]  + __shfl_xor(ar[i],  16);
          float vz = az[i]  + __shfl_xor(az[i],  16);
          float vh = anh[i] + __shfl_xor(anh[i], 16);
          if (quad == 0) {
            const int m = i;
            const float pv = s_prev[m];
            float r = sigm_(vr + fmaf(pv, s_dwih[g],      s_dbr[g]));
            float z = sigm_(vz + fmaf(pv, s_dwih[H_ + g], s_dbz[g]));
            float n = tanh_(fmaf(pv, s_dwih[2 * H_ + g], s_dbin[g]) +
                            r * (vh + s_dbhn[g]));
            float hd = (1.0f - z) * n + z * ctxf[m * 260 + g];
            unsigned short hb = f2bf_(hd);
            hd_t[m * HSTR_ + g]       = __float2bfloat16(hd);
            hd_t[(m + 4) * HSTR_ + g] = __float2bfloat16(hd - bf2f_(hb));
          }
        }
      }
    }
    __syncthreads();

    // P4: fc1 + relu (MFMA, hi/lo fused)
    {
      bf16x8 ad[8];
#pragma unroll
      for (int kk = 0; kk < 8; ++kk)
        ad[kk] = *(const bf16x8*)&hd_t[l16 * HSTR_ + kk * 32 + quad * 8];
#pragma unroll
      for (int s3 = 0; s3 < 2; ++s3) {
        const int c = wv * 2 + s3;
        const int jc = c * 16 + l16;
        const __hip_bfloat16* wb_ = wp + PK_F1_ + (size_t)(c * 8) * 512 + lane * 8;
        f32x4 a1 = {0.f, 0.f, 0.f, 0.f};
#pragma unroll
        for (int kk = 0; kk < 8; ++kk)
          a1 = mfma16(ad[kk], *(const bf16x8*)(wb_ + kk * 512), a1);
#pragma unroll
        for (int i = 0; i < 4; ++i) {
          float v = a1[i] + __shfl_xor(a1[i], 16);
          if (quad == 0)
            f1f[i * 260 + jc] = fmaxf(v + s_f1b[jc], 0.0f);
        }
      }
    }
    __syncthreads();

    // P5: fc2 dot -> out, update prev (chalf==0 wave per row)
    if (chalf == 0) {
      const int c4 = lane * 4;
      float p = 0.f;
#pragma unroll
      for (int j = 0; j < 4; ++j)
        p = fmaf(f1f[drow * 260 + c4 + j], s_f2w[c4 + j], p);
#pragma unroll
      for (int off = 32; off >= 1; off >>= 1) p += __shfl_xor(p, off);
      if (lane == 0) {
        float o = p + s_f2b;
        s_prev[drow] = o;
        dout[(size_t)(b0 + drow) * OUT_ + s] = o;
      }
    }
    __syncthreads();
  }
}

extern "C" void kernel_launch(void* const* d_in, const int* in_sizes, int n_in,
                              void* d_out, int out_size, void* d_ws, size_t ws_size,
                              hipStream_t stream) {
  (void)in_sizes; (void)n_in; (void)out_size; (void)ws_size;
  const float* x    = (const float*)d_in[0];
  const float* h0   = (const float*)d_in[1];
  const float* eWih = (const float*)d_in[2];
  const float* eWhh = (const float*)d_in[3];
  const float* ebih = (const float*)d_in[4];
  const float* ebhh = (const float*)d_in[5];
  const float* dWih = (const float*)d_in[6];
  const float* dWhh = (const float*)d_in[7];
  const float* dbih = (const float*)d_in[8];
  const float* dbhh = (const float*)d_in[9];
  const float* aWq  = (const float*)d_in[10];
  const float* abq  = (const float*)d_in[11];
  const float* f1W  = (const float*)d_in[12];
  const float* f1b  = (const float*)d_in[13];
  const float* f2W  = (const float*)d_in[14];
  const float* f2b  = (const float*)d_in[15];

  char* wsb = (char*)d_ws;
  __hip_bfloat16* hs = (__hip_bfloat16*)wsb;                       // 134,217,728 B
  float* As = (float*)(wsb + (size_t)B_ * T_ * H_ * 2);            // 1 MB
  float* Cs = As + (size_t)B_ * T_;                                // 1 MB
  __hip_bfloat16* wp = (__hip_bfloat16*)((char*)(Cs + (size_t)B_ * T_));

  hipLaunchKernelGGL(af_pack, dim3((PK_TOT_ + 255) / 256), dim3(256), 0, stream,
                     eWih, eWhh, dWhh, f1W, wp);
  hipLaunchKernelGGL(af_encoder, dim3(NBE_), dim3(512), 0, stream,
                     x, h0, ebih, ebhh, aWq, abq, wp, hs, As, Cs);
  hipLaunchKernelGGL(af_decoder, dim3(NBD_), dim3(512), 0, stream,
                     x, dWih, dbih, dbhh, f1b, f2W, f2b, wp, hs, As, Cs,
                     (float*)d_out);
}